// Round 5
// baseline (563.373 us; speedup 1.0000x reference)
//
#include <hip/hip_runtime.h>
#include <hip/hip_bf16.h>
#include <stdint.h>

#define T_TOK 4096
#define E_EXP 8
#define D_DIM 1024
#define F_DIM 4096
#define K_TOP 2
#define CAPC  1024

typedef __attribute__((ext_vector_type(8))) short short8;
typedef __attribute__((ext_vector_type(4))) float f32x4;
typedef __attribute__((ext_vector_type(4))) unsigned short u16x4;
typedef __attribute__((ext_vector_type(8))) unsigned short u16x8;

static __device__ __forceinline__ unsigned short f2bf(float f) {
  union { float f; unsigned u; } v; v.f = f;
  unsigned r = v.u + 0x7fffu + ((v.u >> 16) & 1u);
  return (unsigned short)(r >> 16);
}

static __device__ __forceinline__ void gload_lds16(const void* g, void* l) {
  __builtin_amdgcn_global_load_lds(
      (const __attribute__((address_space(1))) unsigned int*)g,
      (__attribute__((address_space(3))) unsigned int*)l, 16, 0, 0);
}

// ----------------------------------------------------------------- prep -----
// ONE kernel, flat grid, 256 threads/block:
//   blocks [0,8)          : routing select (compact + small bitonic)
//   blocks [8,4104)       : x f32 -> bf16 convert
//   blocks [4104,12296)   : w1/w2 transpose+convert (128x64 tiles)
#define PREP_SEL0   0
#define PREP_CVT0   8
#define PREP_TR0    4104
#define PREP_NBLK   12296

__global__ __launch_bounds__(256) void prep_kernel(
    const float* __restrict__ x,
    const float* __restrict__ rw,
    const float* __restrict__ w1,
    const float* __restrict__ w2,
    unsigned short* __restrict__ xb,
    unsigned short* __restrict__ w1t,   // (E,F,D) bf16
    unsigned short* __restrict__ w2t,   // (E,D,F) bf16
    int* __restrict__ sel_idx,          // (E,CAP) token id or -1
    float* __restrict__ sel_w)          // (E,CAP) routing weight per slot
{
  __shared__ __align__(16) char smem[32768];
  __shared__ int cnt_s;
  const int bid = blockIdx.x;
  const int tid = threadIdx.x;

  if (bid >= PREP_TR0) {
    // ---- transpose+convert: in (R,C) f32 -> out (C,R) bf16, 128r x 64c tile
    const int tb = bid - PREP_TR0;
    const float* inp; unsigned short* outp; int R, C, r0, c0;
    if (tb < 4096) {            // w1: (E,1024,4096) -> (E,4096,1024)
      const int e = tb >> 9, ti = tb & 511;
      R = 1024; C = 4096;
      r0 = (ti & 7) * 128; c0 = (ti >> 3) * 64;
      inp = w1 + (size_t)e * R * C; outp = w1t + (size_t)e * R * C;
    } else {                    // w2: (E,4096,1024) -> (E,1024,4096)
      const int t2 = tb - 4096, e = t2 >> 9, ti = t2 & 511;
      R = 4096; C = 1024;
      r0 = (ti & 31) * 128; c0 = (ti >> 5) * 64;
      inp = w2 + (size_t)e * R * C; outp = w2t + (size_t)e * R * C;
    }
    unsigned short* tile = (unsigned short*)smem;  // [128][66], pad 66
    const int q4 = (tid & 15) * 4, tr = tid >> 4;
    for (int rr = tr; rr < 128; rr += 16) {
      f32x4 v = *(const f32x4*)(inp + (size_t)(r0 + rr) * C + c0 + q4);
      unsigned* t32 = (unsigned*)(tile + rr * 66 + q4);  // idx even: aligned
      t32[0] = (unsigned)f2bf(v.x) | ((unsigned)f2bf(v.y) << 16);
      t32[1] = (unsigned)f2bf(v.z) | ((unsigned)f2bf(v.w) << 16);
    }
    __syncthreads();
    const int l = tid & 15, ccb = tid >> 4;
#pragma unroll
    for (int it = 0; it < 4; ++it) {
      const int cc = ccb + it * 16;
      u16x8 o;
#pragma unroll
      for (int j = 0; j < 8; ++j) o[j] = tile[(l * 8 + j) * 66 + cc];
      *(u16x8*)(outp + (size_t)(c0 + cc) * R + r0 + l * 8) = o;
    }
    return;
  }

  if (bid >= PREP_CVT0) {
    // ---- x f32 -> bf16
    const int i = (bid - PREP_CVT0) * 256 + tid;   // < T*D/4 exactly
    f32x4 v = ((const f32x4*)x)[i];
    u16x4 o = { f2bf(v.x), f2bf(v.y), f2bf(v.z), f2bf(v.w) };
    ((u16x4*)xb)[i] = o;
    return;
  }

  // ---- routing select, one block per expert, 256 threads.
  // Nonzero route_weight == routed. count ~Binomial(T, K/E) ~ 1024+-28.
  // Compact nonzero keys; if count<=CAP all get slots (order arbitrary --
  // combine sums over slots). Else bitonic-sort padded keys descending and
  // take top CAP; key low bits = (4095-t) so ties prefer lower token index
  // (jax.lax.top_k stability).
  unsigned long long* keys = (unsigned long long*)smem;  // up to 4096 (32 KB)
  const int e = bid;
  for (int c = tid; c < CAPC; c += 256) sel_idx[e * CAPC + c] = -1;
  if (tid == 0) cnt_s = 0;
  __syncthreads();
#pragma unroll
  for (int j = 0; j < 16; ++j) {
    const int t = tid * 16 + j;
    const float w = rw[(size_t)t * E_EXP + e];
    if (w > 0.f) {
      const int p = atomicAdd(&cnt_s, 1);
      keys[p] = (((unsigned long long)__float_as_uint(w)) << 32)
                | (unsigned)(4095 - t);
    }
  }
  __syncthreads();
  const int count = cnt_s;
  if (count > CAPC) {
    const int n = (count <= 2048) ? 2048 : 4096;
    for (int i = count + tid; i < n; i += 256) keys[i] = 0ull;
    for (int k = 2; k <= n; k <<= 1) {
      for (int j = k >> 1; j > 0; j >>= 1) {
        __syncthreads();
        for (int i = tid; i < n; i += 256) {
          const int ixj = i ^ j;
          if (ixj > i) {
            const unsigned long long a = keys[i], b = keys[ixj];
            const bool swp = ((i & k) == 0) ? (a < b) : (a > b);  // descending
            if (swp) { keys[i] = b; keys[ixj] = a; }
          }
        }
      }
    }
    __syncthreads();
  }
  const int nout = (count < CAPC) ? count : CAPC;
  for (int c = tid; c < nout; c += 256) {
    const unsigned long long k = keys[c];
    sel_idx[e * CAPC + c] = 4095 - (int)(k & 0xffffffffu);
    sel_w[e * CAPC + c] = __uint_as_float((unsigned)(k >> 32));
  }
}

// ------------------------------------------------------------------ GEMMs ---
// BM=BN=128, BK=64, 256 threads = 4 waves (2x2 of 64x64), 16x16x32 bf16 MFMA,
// global_load_lds width-16 staging. XOR chunk swizzle (chunk ^= row&7) keeps
// ds_read_b128 fragment reads bank-conflict-free. Identity block mapping
// (R3's XCD remap regressed: L2 contention, working set is L3-hot anyway).

__global__ __launch_bounds__(256, 3) void gemm1_kernel(
    const unsigned short* __restrict__ xb,     // (T,D) bf16
    const int* __restrict__ sel_idx,           // (E,CAP)
    const unsigned short* __restrict__ w1t,    // (E,F,D) bf16
    const float* __restrict__ b1,              // (E,F)
    unsigned short* __restrict__ H)            // (E,CAP,F) bf16
{
  __shared__ __align__(16) unsigned short Asm[128 * 64];
  __shared__ __align__(16) unsigned short Bsm[128 * 64];
  const int e = blockIdx.z;
  const int m0 = blockIdx.y * 128;
  const int n0 = blockIdx.x * 128;
  const int tid = threadIdx.x;
  const int lane = tid & 63, wv = tid >> 6;
  const int wm = (wv >> 1) * 64, wn = (wv & 1) * 64;
  const int lrow = lane & 15, quad = lane >> 4;

  const int rbase = tid >> 3, seg = tid & 7;
  const int cs = seg ^ (rbase & 7);
  const unsigned short* gA[4];
  const unsigned short* gB[4];
  char* lA[4];
  char* lB[4];
  const unsigned short* w1e = w1t + (size_t)e * F_DIM * D_DIM;
#pragma unroll
  for (int it = 0; it < 4; ++it) {
    const int row = rbase + it * 32;
    int t = sel_idx[e * CAPC + m0 + row];
    if (t < 0) t = 0;
    gA[it] = xb + (size_t)t * D_DIM + cs * 8;
    gB[it] = w1e + (size_t)(n0 + row) * D_DIM + cs * 8;
    lA[it] = (char*)Asm + it * 4096 + wv * 1024;
    lB[it] = (char*)Bsm + it * 4096 + wv * 1024;
  }

  f32x4 acc[4][4];
#pragma unroll
  for (int a = 0; a < 4; ++a)
#pragma unroll
    for (int b = 0; b < 4; ++b) acc[a][b] = (f32x4){0.f, 0.f, 0.f, 0.f};

  const int sw = lrow & 7;
  for (int k0 = 0; k0 < D_DIM; k0 += 64) {
#pragma unroll
    for (int it = 0; it < 4; ++it) { gload_lds16(gA[it], lA[it]); gA[it] += 64; }
#pragma unroll
    for (int it = 0; it < 4; ++it) { gload_lds16(gB[it], lB[it]); gB[it] += 64; }
    __syncthreads();
#pragma unroll
    for (int h = 0; h < 2; ++h) {
      short8 af[4], bf[4];
#pragma unroll
      for (int mt = 0; mt < 4; ++mt)
        af[mt] = *(const short8*)(Asm + (wm + mt * 16 + lrow) * 64 +
                                  (((h << 2) + quad) ^ sw) * 8);
#pragma unroll
      for (int nt = 0; nt < 4; ++nt)
        bf[nt] = *(const short8*)(Bsm + (wn + nt * 16 + lrow) * 64 +
                                  (((h << 2) + quad) ^ sw) * 8);
#pragma unroll
      for (int mt = 0; mt < 4; ++mt)
#pragma unroll
        for (int nt = 0; nt < 4; ++nt)
          acc[mt][nt] = __builtin_amdgcn_mfma_f32_16x16x32_bf16(
              af[mt], bf[nt], acc[mt][nt], 0, 0, 0);
    }
    __syncthreads();
  }

  // gelu(v) = v * sigmoid(2c(v + a v^3)); exp arg = -2c(v + a v^3)
  const float gk0 = -1.5957691216057308f;           // -2c
  const float gk1 = -0.07135486f;                   // -2c*a
  const float* b1e = b1 + e * F_DIM;
#pragma unroll
  for (int nt = 0; nt < 4; ++nt) {
    const int col = n0 + wn + nt * 16 + lrow;
    const float bias = b1e[col];
#pragma unroll
    for (int mt = 0; mt < 4; ++mt) {
      const int rowb = m0 + wm + mt * 16 + quad * 4;
#pragma unroll
      for (int i = 0; i < 4; ++i) {
        const float v = acc[mt][nt][i] + bias;
        const float q = v * fmaf(gk1, v * v, gk0);
        const float hv = v * __builtin_amdgcn_rcpf(1.f + __expf(q));
        H[((size_t)e * CAPC + rowb + i) * F_DIM + col] = f2bf(hv);
      }
    }
  }
}

// split-K=2 (blockIdx.z = e + 8*ks) with FUSED combine: each output element
// is scaled by its slot's routing weight and atomically added into y[t][col].
// y is pre-zeroed (memsetAsync); dropped slots (t<0) are skipped, so dropped
// tokens stay 0 -- matching the reference's zeroed slot matrix.
__global__ __launch_bounds__(256, 3) void gemm2_kernel(
    const unsigned short* __restrict__ H,      // (E,CAP,F) bf16
    const unsigned short* __restrict__ w2t,    // (E,D,F) bf16
    const float* __restrict__ b2,              // (E,D)
    const int* __restrict__ sel_idx,           // (E,CAP)
    const float* __restrict__ sel_w,           // (E,CAP)
    float* __restrict__ y)                     // (T,D) f32, pre-zeroed
{
  __shared__ __align__(16) unsigned short Asm[128 * 64];
  __shared__ __align__(16) unsigned short Bsm[128 * 64];
  __shared__ int rt[128];
  __shared__ float rww[128];
  const int e = blockIdx.z & 7;
  const int ks = blockIdx.z >> 3;
  const int m0 = blockIdx.y * 128;
  const int n0 = blockIdx.x * 128;
  const int kbase = ks * (F_DIM / 2);
  const int tid = threadIdx.x;
  const int lane = tid & 63, wv = tid >> 6;
  const int wm = (wv >> 1) * 64, wn = (wv & 1) * 64;
  const int lrow = lane & 15, quad = lane >> 4;

  if (tid < 128) {
    rt[tid] = sel_idx[e * CAPC + m0 + tid];
    rww[tid] = sel_w[e * CAPC + m0 + tid];
  }

  const int rbase = tid >> 3, seg = tid & 7;
  const int cs = seg ^ (rbase & 7);
  const unsigned short* gA[4];
  const unsigned short* gB[4];
  char* lA[4];
  char* lB[4];
  const unsigned short* He = H + (size_t)e * CAPC * F_DIM;
  const unsigned short* w2e = w2t + (size_t)e * D_DIM * F_DIM;
#pragma unroll
  for (int it = 0; it < 4; ++it) {
    const int row = rbase + it * 32;
    gA[it] = He + (size_t)(m0 + row) * F_DIM + kbase + cs * 8;
    gB[it] = w2e + (size_t)(n0 + row) * F_DIM + kbase + cs * 8;
    lA[it] = (char*)Asm + it * 4096 + wv * 1024;
    lB[it] = (char*)Bsm + it * 4096 + wv * 1024;
  }

  f32x4 acc[4][4];
#pragma unroll
  for (int a = 0; a < 4; ++a)
#pragma unroll
    for (int b = 0; b < 4; ++b) acc[a][b] = (f32x4){0.f, 0.f, 0.f, 0.f};

  const int sw = lrow & 7;
  for (int k0 = 0; k0 < F_DIM / 2; k0 += 64) {
#pragma unroll
    for (int it = 0; it < 4; ++it) { gload_lds16(gA[it], lA[it]); gA[it] += 64; }
#pragma unroll
    for (int it = 0; it < 4; ++it) { gload_lds16(gB[it], lB[it]); gB[it] += 64; }
    __syncthreads();
#pragma unroll
    for (int h = 0; h < 2; ++h) {
      short8 af[4], bf[4];
#pragma unroll
      for (int mt = 0; mt < 4; ++mt)
        af[mt] = *(const short8*)(Asm + (wm + mt * 16 + lrow) * 64 +
                                  (((h << 2) + quad) ^ sw) * 8);
#pragma unroll
      for (int nt = 0; nt < 4; ++nt)
        bf[nt] = *(const short8*)(Bsm + (wn + nt * 16 + lrow) * 64 +
                                  (((h << 2) + quad) ^ sw) * 8);
#pragma unroll
      for (int mt = 0; mt < 4; ++mt)
#pragma unroll
        for (int nt = 0; nt < 4; ++nt)
          acc[mt][nt] = __builtin_amdgcn_mfma_f32_16x16x32_bf16(
              af[mt], bf[nt], acc[mt][nt], 0, 0, 0);
    }
    __syncthreads();
  }

  const float* b2e = b2 + e * D_DIM;
#pragma unroll
  for (int nt = 0; nt < 4; ++nt) {
    const int col = n0 + wn + nt * 16 + lrow;
    const float bias = (ks == 0) ? b2e[col] : 0.f;
#pragma unroll
    for (int mt = 0; mt < 4; ++mt) {
      const int rowb = wm + mt * 16 + quad * 4;   // local row in [0,128)
#pragma unroll
      for (int i = 0; i < 4; ++i) {
        const int row = rowb + i;
        const int t = rt[row];
        if (t >= 0)
          atomicAdd(&y[(size_t)t * D_DIM + col],
                    rww[row] * (acc[mt][nt][i] + bias));
      }
    }
  }
}

// ----------------------------------------------------------------- launch ---
extern "C" void kernel_launch(void* const* d_in, const int* in_sizes, int n_in,
                              void* d_out, int out_size, void* d_ws, size_t ws_size,
                              hipStream_t stream) {
  (void)in_sizes; (void)n_in; (void)out_size; (void)ws_size;
  const float* x  = (const float*)d_in[0];
  // d_in[1] = route_mask (bool) -- unused; mask == (route_weight > 0)
  const float* rw = (const float*)d_in[2];
  const float* w1 = (const float*)d_in[3];
  const float* b1 = (const float*)d_in[4];
  const float* w2 = (const float*)d_in[5];
  const float* b2 = (const float*)d_in[6];
  float* y = (float*)d_out;

  char* ws = (char*)d_ws;
  size_t off = 0;
  auto alloc = [&](size_t bytes) {
    void* p = ws + off;
    off += (bytes + 255) & ~(size_t)255;
    return p;
  };
  unsigned short* xb  = (unsigned short*)alloc((size_t)T_TOK * D_DIM * 2);
  unsigned short* w1t = (unsigned short*)alloc((size_t)E_EXP * F_DIM * D_DIM * 2);
  unsigned short* w2t = (unsigned short*)alloc((size_t)E_EXP * D_DIM * F_DIM * 2);
  unsigned short* H   = (unsigned short*)alloc((size_t)E_EXP * CAPC * F_DIM * 2);
  int* sel_idx        = (int*)alloc((size_t)E_EXP * CAPC * 4);
  float* sel_w        = (float*)alloc((size_t)E_EXP * CAPC * 4);

  // 1) zero the output (fused-combine atomics accumulate into it; dropped
  //    tokens must read 0)
  hipMemsetAsync(y, 0, (size_t)T_TOK * D_DIM * 4, stream);

  // 2) fused prep: routing select + x convert + both weight transposes
  prep_kernel<<<PREP_NBLK, 256, 0, stream>>>(
      x, rw, w1, w2, xb, w1t, w2t, sel_idx, sel_w);

  // 3) expert MLP; gemm2 epilogue scatters weighted results into y
  gemm1_kernel<<<dim3(F_DIM / 128, CAPC / 128, E_EXP), 256, 0, stream>>>(
      xb, sel_idx, w1t, b1, H);
  gemm2_kernel<<<dim3(D_DIM / 128, CAPC / 128, E_EXP * 2), 256, 0, stream>>>(
      H, w2t, b2, sel_idx, sel_w, y);
}